// Round 11
// baseline (122.163 us; speedup 1.0000x reference)
//
#include <hip/hip_runtime.h>

// Problem constants (from reference setup_inputs): B=2, H=W=128.
#define B_ITEMS 2
#define W_IMG   128
#define N_PTS   16384          // H*W
#define CH_GRID 1024           // >= max Utot = 4*ceil(16384/64)

// ---------------------------------------------------------------------------
// Kernel 1: compaction (unchanged since R7 — proven correct & fast). 256
// blocks x 256 thr; target s = blockIdx.x>>6 (0:P0 1:P1 2:G0 3:G1).
// Block-local ballot scan -> ONE global atomicAdd per block.
//   raw[pos] = (x, y, z, |q|^2)        row side
//   tf [pos] = (-2x, -2y, -2z, |q|^2)  col side: d = |p|^2 + fma3(p, tf)
// Block 0/tid 0 zeroes out[0] (stream order precedes chamfer's atomicAdds).
// ---------------------------------------------------------------------------
__global__ __launch_bounds__(256) void prep_kernel(
        const float* __restrict__ pred,
        const float* __restrict__ gt,
        const int*   __restrict__ mask,
        const float* fxp, const float* fyp,
        const float* cxp, const float* cyp,
        int*    __restrict__ cnt,       // [0]=np0 [1]=np1 [2]=ng0 [3]=ng1
        float4* __restrict__ pR, float4* __restrict__ gR,   // raw   [B][N]
        float4* __restrict__ pT, float4* __restrict__ gT,   // transf[B][N]
        float*  __restrict__ out) {
    int s    = blockIdx.x >> 6;
    int b    = s & 1;
    int isG  = s >> 1;
    int tid  = threadIdx.x;
    int idx  = (blockIdx.x & 63) * 256 + tid;
    int lane = tid & 63, w = tid >> 6;

    if (blockIdx.x == 0 && tid == 0) out[0] = 0.0f;

    float x, y, z;
    if (!isG) {
        float fx = *fxp, fy = *fyp, cx = *cxp, cy = *cyp;
        float u = (float)(idx & (W_IMG - 1));
        float v = (float)(idx >> 7);
        z = pred[b * N_PTS + idx];
        x = (u - cx) / fx * z;
        y = (v - cy) / fy * z;
    } else {
        x = gt[(b * 3 + 0) * N_PTS + idx];
        y = gt[(b * 3 + 1) * N_PTS + idx];
        z = gt[(b * 3 + 2) * N_PTS + idx];
    }
    int  mv = mask[b * N_PTS + idx];
    bool ok = (mv > 0) && (((x + y) + z) != 0.0f);

    unsigned long long bal = __ballot(ok);
    int nw  = __popcll(bal);
    int pre = __popcll(bal & ((1ull << lane) - 1ull));

    __shared__ int wbase[4];
    __shared__ int blockbase;
    if (lane == 0) wbase[w] = nw;
    __syncthreads();
    if (tid == 0) {
        int s0 = 0;
#pragma unroll
        for (int i = 0; i < 4; ++i) { int t = wbase[i]; wbase[i] = s0; s0 += t; }
        blockbase = s0 ? atomicAdd(&cnt[s], s0) : 0;
    }
    __syncthreads();

    if (ok) {
        int pos = blockbase + wbase[w] + pre;
        float ps = fmaf(z, z, fmaf(y, y, x * x));
        float4* __restrict__ raw = (isG ? gR : pR) + b * N_PTS;
        float4* __restrict__ tf  = (isG ? gT : pT) + b * N_PTS;
        raw[pos] = make_float4(x, y, z, ps);
        tf[pos]  = make_float4(-2.0f * x, -2.0f * y, -2.0f * z, ps);
    }
}

// ---------------------------------------------------------------------------
// Kernel 2: unfused direct-sum chamfer, 4 VALU ops/pair. R10 post-mortem:
// float4-slot LDS padding cannot change b128 banking (any 16-B-slot
// permutation averages 4 lanes/bank-quartet; b128 at 16-B stride is already
// the full-BW pattern, ~12 cyc). New structure attacks the two remaining
// stall theories at once:
//   * tc=64 full-wave col split + 16 WAVE-UNIFORM rows/wave: each b128 read
//     feeds 16 rows (vs 8) -> LDS pipe load halves to ~9% of VALU issue.
//   * 512-col double-buffered tiles -> 16 barriers/unit (vs 32).
// Unit = 64 rows (wave w owns rows rowbase+w*16..+15, uniform across lanes
// -> scalar-load friendly); lanes split cols 4-deep per 512-tile. Row-min
// fold: 6 shfl_xor per rm (wave-uniform result), lane-a cndmask select,
// per-row |p|^2 + clamp, 4-lane-group sum, ONE atomicAdd per wave.
// No LDS fold pass. Utot ~ 512 contiguous -> 2 blocks/CU, 2 waves/SIMD.
// ---------------------------------------------------------------------------
__global__ __launch_bounds__(256, 4) void chamfer_kernel(
        const int*    __restrict__ cnt,
        const float4* __restrict__ pR, const float4* __restrict__ gR,
        const float4* __restrict__ pT, const float4* __restrict__ gT,
        float* __restrict__ out) {
    int np0 = cnt[0], np1 = cnt[1], ng0 = cnt[2], ng1 = cnt[3];
    int naArr[4] = {np0, ng0, np1, ng1};
    int nbArr[4] = {ng0, np0, ng1, np1};
    const float4* Arow[4] = {pR, gR, pR + N_PTS, gR + N_PTS};
    const float4* Bcol[4] = {gT, pT, gT + N_PTS, pT + N_PTS};

    int units[4];
    int Utot = 0;
#pragma unroll
    for (int i = 0; i < 4; ++i) {
        units[i] = (naArr[i] > 0 && nbArr[i] > 0) ? ((naArr[i] + 63) >> 6) : 0;
        Utot += units[i];
    }
    int u = blockIdx.x;
    if (u >= Utot) return;
    int s = 0;
    while (u >= units[s]) { u -= units[s]; ++s; }
    int na = naArr[s], nb = nbArr[s];
    const float4* __restrict__ A  = Arow[s];
    const float4* __restrict__ Bp = Bcol[s];
    int rowbase = u * 64;

    int tid  = threadIdx.x;
    int w    = tid >> 6;                 // wave id (0..3)
    int lane = tid & 63;

    // 16 wave-uniform rows per wave: row = rowbase + w*16 + a. Max index
    // rowbase+63 <= 16383 (capacity) always; rows >= na gated at the end.
    // (ws poison 0xAA reads as ~-3e-13, finite -> no NaN/Inf hazard.)
    float px[16], py[16], pz[16], rm[16];
#pragma unroll
    for (int a = 0; a < 16; ++a) {
        float4 v = A[rowbase + w * 16 + a];      // wave-uniform address
        px[a] = v.x; py[a] = v.y; pz[a] = v.z;
        rm[a] = 3.4e38f;
    }

    __shared__ float4 sB[2][512];                // 512-col tiles, dbuf (16 KB)
    int ntiles = (nb + 511) >> 9;                // >= 1 (nb > 0 by gating)

    // stage tile 0 (branchless masked: clamp index, select sentinel)
#pragma unroll
    for (int k = 0; k < 2; ++k) {
        int j = k * 256 + tid;
        float4 v = Bp[min(j, N_PTS - 1)];
        bool okc = j < nb;
        float4 r;
        r.x = okc ? v.x : 0.0f;
        r.y = okc ? v.y : 0.0f;
        r.z = okc ? v.z : 0.0f;
        r.w = okc ? v.w : 3.4e38f;               // sentinel col never wins min
        sB[0][k * 256 + tid] = r;
    }
    __syncthreads();

    for (int t = 0; t < ntiles; ++t) {
        float4 r0, r1;                           // prefetch tile t+1 (global)
        bool have = (t + 1 < ntiles);
        if (have) {
            int j0 = (t + 1) * 512 + tid;
            int j1 = j0 + 256;
            float4 v0 = Bp[min(j0, N_PTS - 1)];
            float4 v1 = Bp[min(j1, N_PTS - 1)];
            bool k0 = j0 < nb, k1 = j1 < nb;
            r0.x = k0 ? v0.x : 0.0f; r0.y = k0 ? v0.y : 0.0f;
            r0.z = k0 ? v0.z : 0.0f; r0.w = k0 ? v0.w : 3.4e38f;
            r1.x = k1 ? v1.x : 0.0f; r1.y = k1 ? v1.y : 0.0f;
            r1.z = k1 ? v1.z : 0.0f; r1.w = k1 ? v1.w : 3.4e38f;
        }
        const float4* __restrict__ buf = sB[t & 1] + lane;
#pragma unroll
        for (int cb = 0; cb < 8; ++cb) {
            float4 c = buf[cb * 64];             // b128, full-BW pattern
#pragma unroll
            for (int a = 0; a < 16; ++a)
                rm[a] = fminf(rm[a],
                    fmaf(px[a], c.x, fmaf(py[a], c.y, fmaf(pz[a], c.z, c.w))));
        }
        if (have) {
            sB[(t + 1) & 1][tid] = r0;
            sB[(t + 1) & 1][256 + tid] = r1;
        }
        __syncthreads();                          // readers done + write visible
    }

    // fold each rm over all 64 lanes (result wave-uniform)
#pragma unroll
    for (int a = 0; a < 16; ++a) {
        float v = rm[a];
        v = fminf(v, __shfl_xor(v, 1, 64));
        v = fminf(v, __shfl_xor(v, 2, 64));
        v = fminf(v, __shfl_xor(v, 4, 64));
        v = fminf(v, __shfl_xor(v, 8, 64));
        v = fminf(v, __shfl_xor(v, 16, 64));
        v = fminf(v, __shfl_xor(v, 32, 64));
        rm[a] = v;
    }
    // lane a (a<16) picks rm[a]; add |p|^2, clamp, gate row<na
    float acc = 0.0f;
#pragma unroll
    for (int a = 0; a < 16; ++a)
        acc = (lane == a) ? rm[a] : acc;
    if (lane < 16) {
        int row = rowbase + w * 16 + lane;
        float ps = A[row].w;
        acc = (row < na) ? fmaxf(acc + ps, 0.0f) : 0.0f;
    } else {
        acc = 0.0f;
    }
    // sum lanes 0..15 (xor 1,2,4,8 stays in 16-group; others hold 0)
    acc += __shfl_xor(acc, 1, 64);
    acc += __shfl_xor(acc, 2, 64);
    acc += __shfl_xor(acc, 4, 64);
    acc += __shfl_xor(acc, 8, 64);
    if (lane == 0) atomicAdd(out, acc * (1.0f / B_ITEMS));
}

extern "C" void kernel_launch(void* const* d_in, const int* in_sizes, int n_in,
                              void* d_out, int out_size, void* d_ws, size_t ws_size,
                              hipStream_t stream) {
    const float* pred = (const float*)d_in[0];
    const float* gt   = (const float*)d_in[1];
    const int*   mask = (const int*)  d_in[2];
    const float* fx   = (const float*)d_in[3];
    const float* fy   = (const float*)d_in[4];
    const float* cx   = (const float*)d_in[5];
    const float* cy   = (const float*)d_in[6];
    float* out = (float*)d_out;

    // ws: [0,256) cnt | pR 512K | gR 512K | pT 512K | gT 512K  (~2.1 MB)
    char* ws = (char*)d_ws;
    size_t SEG = (size_t)B_ITEMS * N_PTS * 16;
    int*    cnt = (int*)ws;
    float4* pR  = (float4*)(ws + 256);
    float4* gR  = (float4*)(ws + 256 + SEG);
    float4* pT  = (float4*)(ws + 256 + 2 * SEG);
    float4* gT  = (float4*)(ws + 256 + 3 * SEG);

    hipMemsetAsync(cnt, 0, 16, stream);

    prep_kernel<<<dim3(256), 256, 0, stream>>>(
        pred, gt, mask, fx, fy, cx, cy, cnt, pR, gR, pT, gT, out);

    chamfer_kernel<<<dim3(CH_GRID), 256, 0, stream>>>(
        cnt, pR, gR, pT, gT, out);
}

// Round 12
// 101.577 us; speedup vs baseline: 1.2027x; 1.2027x over previous
//
#include <hip/hip_runtime.h>

// Problem constants (from reference setup_inputs): B=2, H=W=128.
#define B_ITEMS 2
#define W_IMG   128
#define N_PTS   16384          // H*W
#define CH_GRID 1024           // >= max Utot = 4*ceil(16384/64)

// ---------------------------------------------------------------------------
// Kernel 1: compaction (unchanged since R7 — proven correct & fast). 256
// blocks x 256 thr; target s = blockIdx.x>>6 (0:P0 1:P1 2:G0 3:G1).
// Block-local ballot scan -> ONE global atomicAdd per block.
//   raw[pos] = (x, y, z, |q|^2)        row side
//   tf [pos] = (-2x, -2y, -2z, |q|^2)  col side: d = |p|^2 + fma3(p, tf)
// Block 0/tid 0 zeroes out[0] (stream order precedes chamfer's atomicAdds).
// ---------------------------------------------------------------------------
__global__ __launch_bounds__(256) void prep_kernel(
        const float* __restrict__ pred,
        const float* __restrict__ gt,
        const int*   __restrict__ mask,
        const float* fxp, const float* fyp,
        const float* cxp, const float* cyp,
        int*    __restrict__ cnt,       // [0]=np0 [1]=np1 [2]=ng0 [3]=ng1
        float4* __restrict__ pR, float4* __restrict__ gR,   // raw   [B][N]
        float4* __restrict__ pT, float4* __restrict__ gT,   // transf[B][N]
        float*  __restrict__ out) {
    int s    = blockIdx.x >> 6;
    int b    = s & 1;
    int isG  = s >> 1;
    int tid  = threadIdx.x;
    int idx  = (blockIdx.x & 63) * 256 + tid;
    int lane = tid & 63, w = tid >> 6;

    if (blockIdx.x == 0 && tid == 0) out[0] = 0.0f;

    float x, y, z;
    if (!isG) {
        float fx = *fxp, fy = *fyp, cx = *cxp, cy = *cyp;
        float u = (float)(idx & (W_IMG - 1));
        float v = (float)(idx >> 7);
        z = pred[b * N_PTS + idx];
        x = (u - cx) / fx * z;
        y = (v - cy) / fy * z;
    } else {
        x = gt[(b * 3 + 0) * N_PTS + idx];
        y = gt[(b * 3 + 1) * N_PTS + idx];
        z = gt[(b * 3 + 2) * N_PTS + idx];
    }
    int  mv = mask[b * N_PTS + idx];
    bool ok = (mv > 0) && (((x + y) + z) != 0.0f);

    unsigned long long bal = __ballot(ok);
    int nw  = __popcll(bal);
    int pre = __popcll(bal & ((1ull << lane) - 1ull));

    __shared__ int wbase[4];
    __shared__ int blockbase;
    if (lane == 0) wbase[w] = nw;
    __syncthreads();
    if (tid == 0) {
        int s0 = 0;
#pragma unroll
        for (int i = 0; i < 4; ++i) { int t = wbase[i]; wbase[i] = s0; s0 += t; }
        blockbase = s0 ? atomicAdd(&cnt[s], s0) : 0;
    }
    __syncthreads();

    if (ok) {
        int pos = blockbase + wbase[w] + pre;
        float ps = fmaf(z, z, fmaf(y, y, x * x));
        float4* __restrict__ raw = (isG ? gR : pR) + b * N_PTS;
        float4* __restrict__ tf  = (isG ? gT : pT) + b * N_PTS;
        raw[pos] = make_float4(x, y, z, ps);
        tf[pos]  = make_float4(-2.0f * x, -2.0f * y, -2.0f * z, ps);
    }
}

// ---------------------------------------------------------------------------
// Kernel 2: unfused direct-sum chamfer, 4 VALU ops/pair, LDS double-buffered
// B staging — EXACT R9 structure (best measured: chamfer ~35 us, total
// 104.2) with ONE delta: 512-col staged tiles instead of 256 (halves the
// barrier count; VALU, LDS-bytes/col, TLP all unchanged — clean A/B).
// R10 lesson: float4-slot LDS padding cannot change b128 banking. R11
// lesson: 16-row/thread wave-uniform layout starves VGPRs (64 = arrays
// alone) and regresses; 8 rows/thread is the sweet spot.
// Unit = 64 A-rows x all B-cols, contiguous unit ids -> uniform CU fill.
// Block 256 = (tc = tid&31, tr = tid>>5): thread owns 8 rows; per 512-col
// tile it global-loads TWO float4 (in flight under ~512 VALU ops, ds_write
// at tile end), and ds_read_b128's 16 cols-chunks from LDS. Tail staged
// with sentinel w=+3e38 -> uniform unmasked inner loop. One barrier/tile.
// Row-min in-register, fold over tc (5 shfl_xor), per-row |p|^2 + clamp,
// one atomicAdd per unit.
// ---------------------------------------------------------------------------
__global__ __launch_bounds__(256, 4) void chamfer_kernel(
        const int*    __restrict__ cnt,
        const float4* __restrict__ pR, const float4* __restrict__ gR,
        const float4* __restrict__ pT, const float4* __restrict__ gT,
        float* __restrict__ out) {
    int np0 = cnt[0], np1 = cnt[1], ng0 = cnt[2], ng1 = cnt[3];
    int naArr[4] = {np0, ng0, np1, ng1};
    int nbArr[4] = {ng0, np0, ng1, np1};
    const float4* Arow[4] = {pR, gR, pR + N_PTS, gR + N_PTS};
    const float4* Bcol[4] = {gT, pT, gT + N_PTS, pT + N_PTS};

    int units[4];
    int Utot = 0;
#pragma unroll
    for (int i = 0; i < 4; ++i) {
        units[i] = (naArr[i] > 0 && nbArr[i] > 0) ? ((naArr[i] + 63) >> 6) : 0;
        Utot += units[i];
    }
    int u = blockIdx.x;
    if (u >= Utot) return;
    int s = 0;
    while (u >= units[s]) { u -= units[s]; ++s; }
    int na = naArr[s], nb = nbArr[s];
    const float4* __restrict__ A  = Arow[s];
    const float4* __restrict__ Bp = Bcol[s];
    int rowbase = u * 64;

    int tid = threadIdx.x;
    int tc = tid & 31, tr = tid >> 5;

    // 8 rows/thread: row = rowbase + a*8 + tr (rows >= na gated at the end;
    // ws poison 0xAA reads as ~-3e-13, finite -> no NaN/Inf hazard).
    float px[8], py[8], pz[8], rm[8];
#pragma unroll
    for (int a = 0; a < 8; ++a) {
        float4 v = A[rowbase + a * 8 + tr];      // < N_PTS capacity always
        px[a] = v.x; py[a] = v.y; pz[a] = v.z;
        rm[a] = 3.4e38f;
    }

    __shared__ float4 sB[2][512];                // 512-col tiles, dbuf (16 KB)
    __shared__ float  smin[64];
    int ntiles = (nb + 511) >> 9;                // >= 1 (nb > 0 by gating)

    // stage tile 0 (branchless masked: clamp index, select sentinel)
#pragma unroll
    for (int k = 0; k < 2; ++k) {
        int j = k * 256 + tid;
        float4 v = Bp[min(j, N_PTS - 1)];
        bool okc = j < nb;
        float4 r;
        r.x = okc ? v.x : 0.0f;
        r.y = okc ? v.y : 0.0f;
        r.z = okc ? v.z : 0.0f;
        r.w = okc ? v.w : 3.4e38f;               // sentinel col never wins min
        sB[0][k * 256 + tid] = r;
    }
    __syncthreads();

    for (int t = 0; t < ntiles; ++t) {
        float4 r0, r1;                           // prefetch tile t+1 (global)
        bool have = (t + 1 < ntiles);
        if (have) {
            int j0 = (t + 1) * 512 + tid;
            int j1 = j0 + 256;
            float4 v0 = Bp[min(j0, N_PTS - 1)];
            float4 v1 = Bp[min(j1, N_PTS - 1)];
            bool k0 = j0 < nb, k1 = j1 < nb;
            r0.x = k0 ? v0.x : 0.0f; r0.y = k0 ? v0.y : 0.0f;
            r0.z = k0 ? v0.z : 0.0f; r0.w = k0 ? v0.w : 3.4e38f;
            r1.x = k1 ? v1.x : 0.0f; r1.y = k1 ? v1.y : 0.0f;
            r1.z = k1 ? v1.z : 0.0f; r1.w = k1 ? v1.w : 3.4e38f;
        }
        const float4* __restrict__ buf = sB[t & 1] + tc;
#pragma unroll
        for (int cb = 0; cb < 16; ++cb) {
            float4 c = buf[cb * 32];             // b128, half-wave broadcast
#pragma unroll
            for (int a = 0; a < 8; ++a)
                rm[a] = fminf(rm[a],
                    fmaf(px[a], c.x, fmaf(py[a], c.y, fmaf(pz[a], c.z, c.w))));
        }
        if (have) {
            sB[(t + 1) & 1][tid] = r0;
            sB[(t + 1) & 1][256 + tid] = r1;
        }
        __syncthreads();                          // readers done + write visible
    }

    // fold over tc (lane bits 0..4)
#pragma unroll
    for (int a = 0; a < 8; ++a) {
        float v = rm[a];
        v = fminf(v, __shfl_xor(v, 1, 64));
        v = fminf(v, __shfl_xor(v, 2, 64));
        v = fminf(v, __shfl_xor(v, 4, 64));
        v = fminf(v, __shfl_xor(v, 8, 64));
        v = fminf(v, __shfl_xor(v, 16, 64));
        rm[a] = v;
    }
    if (tc == 0) {                               // lanes 0 & 32 of each wave
#pragma unroll
        for (int a = 0; a < 8; ++a) smin[a * 8 + tr] = rm[a];
    }
    __syncthreads();
    if (tid < 64) {
        int row = rowbase + tid;                 // matches smin[tid] mapping
        float v  = smin[tid];
        float ps = A[row].w;                     // |p|^2 (L1-hot reload)
        float contrib = (row < na) ? fmaxf(v + ps, 0.0f) : 0.0f;
#pragma unroll
        for (int off = 32; off > 0; off >>= 1)
            contrib += __shfl_down(contrib, off, 64);
        if (tid == 0) atomicAdd(out, contrib * (1.0f / B_ITEMS));
    }
}

extern "C" void kernel_launch(void* const* d_in, const int* in_sizes, int n_in,
                              void* d_out, int out_size, void* d_ws, size_t ws_size,
                              hipStream_t stream) {
    const float* pred = (const float*)d_in[0];
    const float* gt   = (const float*)d_in[1];
    const int*   mask = (const int*)  d_in[2];
    const float* fx   = (const float*)d_in[3];
    const float* fy   = (const float*)d_in[4];
    const float* cx   = (const float*)d_in[5];
    const float* cy   = (const float*)d_in[6];
    float* out = (float*)d_out;

    // ws: [0,256) cnt | pR 512K | gR 512K | pT 512K | gT 512K  (~2.1 MB)
    char* ws = (char*)d_ws;
    size_t SEG = (size_t)B_ITEMS * N_PTS * 16;
    int*    cnt = (int*)ws;
    float4* pR  = (float4*)(ws + 256);
    float4* gR  = (float4*)(ws + 256 + SEG);
    float4* pT  = (float4*)(ws + 256 + 2 * SEG);
    float4* gT  = (float4*)(ws + 256 + 3 * SEG);

    hipMemsetAsync(cnt, 0, 16, stream);

    prep_kernel<<<dim3(256), 256, 0, stream>>>(
        pred, gt, mask, fx, fy, cx, cy, cnt, pR, gR, pT, gT, out);

    chamfer_kernel<<<dim3(CH_GRID), 256, 0, stream>>>(
        cnt, pR, gR, pT, gT, out);
}